// Round 4
// baseline (7505.819 us; speedup 1.0000x reference)
//
#include <hip/hip_runtime.h>
#include <stdint.h>

#define B_ 64
#define T_ 2048
#define I_ 512
#define H_ 512

typedef short bf16x8 __attribute__((ext_vector_type(8)));
typedef float f32x4 __attribute__((ext_vector_type(4)));

__device__ __forceinline__ unsigned short f2bf(float f) {
  union { float f; unsigned u; } x; x.f = f;
  unsigned r = x.u + 0x7fffu + ((x.u >> 16) & 1u);
  return (unsigned short)(r >> 16);
}
__device__ __forceinline__ float sigm(float x) { return 1.0f / (1.0f + __expf(-x)); }
__device__ __forceinline__ float tanhfast(float x) { return 1.0f - 2.0f / (__expf(2.0f * x) + 1.0f); }

// Kernel 1: zero barrier flags + convert inputs (B,T,I) f32 -> (T,B,I) bf16
__global__ void prep_kernel(const float* __restrict__ in, unsigned short* __restrict__ xbf,
                            unsigned int* __restrict__ flags) {
  int t = blockIdx.x;
  int tid = threadIdx.x;
  if (t == 0) {
    for (int i = tid; i < 1024; i += 256) flags[i] = 0u;
  }
  const int slab = B_ * I_;  // 32768
  for (int idx = tid * 4; idx < slab; idx += 256 * 4) {
    int b = idx >> 9;
    int i = idx & 511;
    const float4 v = *reinterpret_cast<const float4*>(in + ((size_t)b * T_ + t) * I_ + i);
    ushort4 o;
    o.x = f2bf(v.x); o.y = f2bf(v.y); o.z = f2bf(v.z); o.w = f2bf(v.w);
    *reinterpret_cast<ushort4*>(xbf + (size_t)t * slab + idx) = o;
  }
}

// 16 dwordx4 fragment loads, byte offsets 0..960 (kk*64)
#define APPLY16(M) M(0,"0") M(1,"64") M(2,"128") M(3,"192") M(4,"256") M(5,"320") \
  M(6,"384") M(7,"448") M(8,"512") M(9,"576") M(10,"640") M(11,"704") \
  M(12,"768") M(13,"832") M(14,"896") M(15,"960")

// Persistent LSTM kernel: 256 WGs = 4 batch-groups (16 rows) x 64 col-slices (8 h-cols).
// Weights LDS-resident in MFMA B-fragment order; c-state in registers.
// R4: inline-asm load batches (distinct "=v" outputs -> 16 fragments truly in
// flight, ONE vmcnt(0) per phase) + x(t+1) prefetch hidden under poll+h-phase.
__global__ __launch_bounds__(64, 1) void lstm_kernel(
    const float* __restrict__ Wi, const float* __restrict__ bi,
    const float* __restrict__ Wh, const float* __restrict__ bh,
    const unsigned short* __restrict__ xbf,
    unsigned short* __restrict__ hbuf,
    unsigned int* flags,
    float* __restrict__ out, float* __restrict__ hT)
{
  const int wg = blockIdx.x;
  const int bg = wg >> 6;    // batch group 0..3
  const int gc = wg & 63;    // col-slice 0..63
  const int lane = threadIdx.x;

  extern __shared__ char lds[];
  short* Wp = (short*)lds;               // 32 ksteps x 2 tiles x 64 lanes x 8 = 64KB
  float* gates = (float*)(lds + 65536);  // 16 x 32 f32 = 2KB

  // ---- pack weight slice into LDS as B fragments; combined K: [0,512)=Wi, [512,1024)=Wh
  {
    const int n = lane & 31;                                   // gate-col index 0..31
    const int col = ((n >> 3) << 9) + (gc << 3) + (n & 7);     // q*512 + gc*8 + j
    for (int kf = (lane >> 5); kf < 1024; kf += 2) {
      float v = (kf < 512) ? Wi[(size_t)kf * 2048 + col]
                           : Wh[(size_t)(kf - 512) * 2048 + col];
      int kk = kf >> 5;
      int lp = (((kf & 31) >> 3) << 4) + (n & 15);             // B-frag lane
      int tl = n >> 4;                                          // N-tile
      Wp[((((kk << 1) + tl) << 6) + lp) * 8 + (kf & 7)] = (short)f2bf(v);
    }
  }
  const int n0 = lane & 15;
  const int col0 = ((n0 >> 3) << 9) + (gc << 3) + (n0 & 7);
  const int n1 = n0 + 16;
  const int col1 = ((n1 >> 3) << 9) + (gc << 3) + (n1 & 7);
  const float rb0 = bi[col0] + bh[col0];
  const float rb1 = bi[col1] + bh[col1];
  __syncthreads();

  const int bbase = bg << 4;
  const size_t arow = ((size_t)(bbase + (lane & 15))) * 512 + ((lane >> 4) << 3);
  const short* wl = Wp + (lane << 3);
  const int jc = gc << 3;
  const int b_l = lane >> 2;           // local batch row for activation (0..15)
  const int j0 = (lane & 3) << 1;      // h-col pair within slice
  const int brow = bbase + b_l;

  float c0 = 0.f, c1 = 0.f;
  unsigned int* myflag = flags + wg;
  unsigned int* pollflag = flags + (bg << 6) + lane;

  bf16x8 xa[16];
  bf16x8 ha[16];

#define LDX(i, OFF) asm volatile("global_load_dwordx4 %0, %1, off offset:" OFF \
    : "=v"(xa[i]) : "v"(xsrc) : "memory");
#define LDH(i, OFF) asm volatile("global_load_dwordx4 %0, %1, off offset:" OFF " sc0 sc1" \
    : "=v"(ha[i]) : "v"(hsrc) : "memory");

  // ---- prologue: load x(0)
  {
    const unsigned short* xsrc = xbf + arow;
    APPLY16(LDX)
  }
  asm volatile("s_waitcnt vmcnt(0)" ::: "memory");
  __builtin_amdgcn_sched_barrier(0);

  for (int t = 0; t < T_; ++t) {
    f32x4 acc0 = {rb0, rb0, rb0, rb0};
    f32x4 acc1 = {rb1, rb1, rb1, rb1};

    // ---- phase X: MFMA on xa (already loaded & drained)
#pragma unroll
    for (int kk = 0; kk < 16; ++kk) {
      bf16x8 w0 = *reinterpret_cast<const bf16x8*>(wl + (kk << 10));
      bf16x8 w1 = *reinterpret_cast<const bf16x8*>(wl + (kk << 10) + 512);
      acc0 = __builtin_amdgcn_mfma_f32_16x16x32_bf16(xa[kk], w0, acc0, 0, 0, 0);
      acc1 = __builtin_amdgcn_mfma_f32_16x16x32_bf16(xa[kk], w1, acc1, 0, 0, 0);
    }
    __builtin_amdgcn_sched_barrier(0);  // pin MFMA issue before xa reuse below

    // ---- prefetch x(t+1): latency hides under poll + h-phase; drained by the
    //      next vmcnt(0) (h-phase or publish) before consumption next iter
    {
      const int tn = (t + 1 < T_) ? t + 1 : t;
      const unsigned short* xsrc = xbf + (size_t)tn * (B_ * I_) + arow;
      APPLY16(LDX)
    }

    if (t > 0) {
      // ---- wait for whole batch-group to have published h_t
      const unsigned int want = (unsigned int)t;
      while (__hip_atomic_load(pollflag, __ATOMIC_RELAXED, __HIP_MEMORY_SCOPE_AGENT) < want) {}
      asm volatile("" ::: "memory");  // pin h-loads after the poll exit

      // ---- phase H: 16 coherent fragment loads, one drain, then MFMA
      {
        const unsigned short* hsrc = hbuf + (size_t)(t & 1) * (B_ * H_) + arow;
        APPLY16(LDH)
      }
      asm volatile("s_waitcnt vmcnt(0)" ::: "memory");
      __builtin_amdgcn_sched_barrier(0);
#pragma unroll
      for (int kk = 0; kk < 16; ++kk) {
        bf16x8 w0 = *reinterpret_cast<const bf16x8*>(wl + ((kk + 16) << 10));
        bf16x8 w1 = *reinterpret_cast<const bf16x8*>(wl + ((kk + 16) << 10) + 512);
        acc0 = __builtin_amdgcn_mfma_f32_16x16x32_bf16(ha[kk], w0, acc0, 0, 0, 0);
        acc1 = __builtin_amdgcn_mfma_f32_16x16x32_bf16(ha[kk], w1, acc1, 0, 0, 0);
      }
    }

    // C/D layout: col = lane&15, row = (lane>>4)*4 + r  -> remap through LDS
    {
      const int cc = lane & 15;
      const int rb = (lane >> 4) << 2;
#pragma unroll
      for (int r = 0; r < 4; ++r) {
        gates[(rb + r) * 32 + cc] = acc0[r];
        gates[(rb + r) * 32 + 16 + cc] = acc1[r];
      }
    }
    __syncthreads();
    const float* grow = gates + b_l * 32;
    float gi0 = grow[j0],      gi1 = grow[j0 + 1];
    float gf0 = grow[8 + j0],  gf1 = grow[9 + j0];
    float gg0 = grow[16 + j0], gg1 = grow[17 + j0];
    float go0 = grow[24 + j0], go1 = grow[25 + j0];
    __syncthreads();  // protect gates LDS against next-iter overwrite
    float o0 = sigm(go0), o1 = sigm(go1);
    c0 = sigm(gf0) * c0 + sigm(gi0) * tanhfast(gg0);
    c1 = sigm(gf1) * c1 + sigm(gi1) * tanhfast(gg1);
    float h0 = o0 * tanhfast(c0);
    float h1 = o1 * tanhfast(c1);

    // ---- publish h first (critical path), outputs after the flag
    unsigned int hpack = (unsigned int)f2bf(h0) | ((unsigned int)f2bf(h1) << 16);
    unsigned int* hw = (unsigned int*)(hbuf + (size_t)((t + 1) & 1) * (B_ * H_) + (size_t)brow * H_ + jc + j0);
    __hip_atomic_store(hw, hpack, __ATOMIC_RELAXED, __HIP_MEMORY_SCOPE_AGENT);
    // order h-store (acked at coherence point) before flag store; also drains x-prefetch
    asm volatile("s_waitcnt vmcnt(0)" ::: "memory");
    if (lane == 0 && t < T_ - 1)
      __hip_atomic_store(myflag, (unsigned int)(t + 1), __ATOMIC_RELAXED, __HIP_MEMORY_SCOPE_AGENT);

    // reference output per step is o_t (off the sync critical path)
    float* orow = out + ((size_t)brow * T_ + t) * H_ + jc + j0;
    orow[0] = o0; orow[1] = o1;
    if (t == T_ - 1) {
      float* hTo = hT + (size_t)brow * H_ + jc + j0;
      hTo[0] = h0; hTo[1] = h1;
    }
  }
#undef LDX
#undef LDH
}

extern "C" void kernel_launch(void* const* d_in, const int* in_sizes, int n_in,
                              void* d_out, int out_size, void* d_ws, size_t ws_size,
                              hipStream_t stream) {
  const float* inputs = (const float*)d_in[0];
  const float* Wi = (const float*)d_in[1];
  const float* bi = (const float*)d_in[2];
  const float* Wh = (const float*)d_in[3];
  const float* bh = (const float*)d_in[4];
  float* out = (float*)d_out;
  float* hT = out + (size_t)B_ * T_ * H_;

  // workspace layout: [flags 16KB][hbuf 2x64KB][xbf 128MB]
  unsigned int* flags = (unsigned int*)d_ws;
  unsigned short* hbuf = (unsigned short*)((char*)d_ws + 16384);
  unsigned short* xbf = (unsigned short*)((char*)d_ws + 16384 + 2 * B_ * H_ * 2);

  (void)hipFuncSetAttribute((const void*)lstm_kernel,
                            hipFuncAttributeMaxDynamicSharedMemorySize, 67584);

  prep_kernel<<<dim3(T_), dim3(256), 0, stream>>>(inputs, xbf, flags);
  lstm_kernel<<<dim3(256), dim3(64), 67584, stream>>>(Wi, bi, Wh, bh, xbf, hbuf, flags, out, hT);
}